// Round 21
// baseline (250.519 us; speedup 1.0000x reference)
//
#include <hip/hip_runtime.h>
#include <hip/hip_bf16.h>
#include <cstdint>

#define NN 40000
#define NE 100000
#define NEP 100096           // 256-aligned edge count
#define NB 1024
#define MAXN 192             // per-graph LDS node cache capacity

typedef _Float16 halfT;
typedef _Float16 half8 __attribute__((ext_vector_type(8)));
typedef float f32x4 __attribute__((ext_vector_type(4)));

static __device__ __forceinline__ float sigf(float x){ return 1.f/(1.f + __expf(-x)); }
static __device__ __forceinline__ float tanh_f(float x){ float e = __expf(2.f * x); return 1.f - 2.f/(e + 1.f); }

// ---------------- fast zero ----------------
__global__ __launch_bounds__(256) void k_zero(float4* __restrict__ p, int n4){
    int i = blockIdx.x * 256 + threadIdx.x;
    if (i < n4) p[i] = make_float4(0.f, 0.f, 0.f, 0.f);
}

// =====================================================================
// k_setup: one kernel, 7 block-ranges.  [unchanged from R17]
// =====================================================================
__global__ __launch_bounds__(256) void k_setup(
    const float* __restrict__ x, const float* __restrict__ lin0_W, const float* __restrict__ lin0_b,
    const float* __restrict__ ea, const float* __restrict__ W1, const float* __restrict__ b1,
    const float* __restrict__ W2, const float* __restrict__ b2,
    const int* __restrict__ dstA, const int* __restrict__ batch,
    const float* __restrict__ rootW,
    const float* __restrict__ gWih, const float* __restrict__ gWhh,
    const float* __restrict__ lWih, const float* __restrict__ lWhh, const float* __restrict__ lin1_W,
    float* __restrict__ h, halfT* __restrict__ hH, halfT* __restrict__ ehF, halfT* __restrict__ BfF,
    float* __restrict__ deg, halfT* __restrict__ gateB,
    float* __restrict__ lWihT, float* __restrict__ lWhhT, float* __restrict__ lin1T,
    int* __restrict__ starts)
{
    int b = blockIdx.x, tid = threadIdx.x;
    if (b < 1250){
        __shared__ float sW[32 * 30];
        __shared__ float sB[32];
        for (int idx = tid; idx < 960; idx += 256) sW[idx] = lin0_W[idx];
        if (tid < 32) sB[tid] = lin0_b[tid];
        __syncthreads();
        int t8 = b * 256 + tid;             // [0, NN*8)
        int i = t8 >> 3, q4 = t8 & 7;       // node, channel-quad
        const float* xr = x + (size_t)i * 30;
        float xv[30];
        #pragma unroll
        for (int f = 0; f < 30; f++) xv[f] = xr[f];
        float r[4];
        #pragma unroll
        for (int cc = 0; cc < 4; cc++){
            int c = q4 * 4 + cc;
            const float* wr = &sW[c * 30];
            float s = sB[c];
            #pragma unroll
            for (int f = 0; f < 30; f++) s += xv[f] * wr[f];
            r[cc] = fmaxf(s, 0.f);
        }
        *(float4*)(h + (size_t)i * 32 + q4 * 4) = *(float4*)r;
        halfT rh[4];
        #pragma unroll
        for (int cc = 0; cc < 4; cc++) rh[cc] = (halfT)r[cc];
        *(uint2*)(hH + (size_t)i * 32 + q4 * 4) = *(uint2*)rh;
    } else if (b < 7506){
        __shared__ float sW1[128 * 11];
        __shared__ float sb1[128];
        for (int idx = tid; idx < 1408; idx += 256) sW1[idx] = W1[idx];
        if (tid < 128) sb1[tid] = b1[tid];
        __syncthreads();
        int t8 = (b - 1250) * 256 + tid;    // [0, NEP*16)
        int ch = t8 & 63;
        int s4 = (t8 >> 6) & 3;
        int g16 = t8 >> 8;
        int m = ch & 15, q = ch >> 4;       // lane-linear content
        int e = g16 * 16 + m;
        int kb = 32 * s4 + q * 8;
        halfT v[8];
        if (e < NE){
            const float* xr = ea + (size_t)e * 11;
            float xv[11];
            #pragma unroll
            for (int f = 0; f < 11; f++) xv[f] = xr[f];
            #pragma unroll
            for (int i8 = 0; i8 < 8; i8++){
                int k = kb + i8;
                const float* wr = &sW1[k * 11];
                float s = sb1[k];
                #pragma unroll
                for (int f = 0; f < 11; f++) s += xv[f] * wr[f];
                v[i8] = (halfT)fmaxf(s, 0.f);
            }
        } else {
            #pragma unroll
            for (int i8 = 0; i8 < 8; i8++) v[i8] = (halfT)0.f;
        }
        *(half8*)(ehF + (size_t)t8 * 8) = *(half8*)v;
    } else if (b < 8022){
        int gid = (b - 7506) * 256 + tid;   // 129*2*64*8 = 132096
        int i8 = gid & 7;
        int ch = (gid >> 3) & 63;
        int nt = (gid >> 9) & 1;
        int ks = gid >> 10;
        int m = ch & 15, q = ch >> 4;       // lane-linear content
        int o = nt * 16 + m;
        float v;
        if (ks < 128){
            int c = ks >> 2;
            int k = 32 * (ks & 3) + q * 8 + i8;
            v = W2[(size_t)(c * 32 + o) * 128 + k];
        } else {
            int c = q * 8 + i8;
            v = b2[c * 32 + o];
        }
        BfF[gid] = (halfT)v;
    } else if (b < 8413){
        int e = (b - 8022) * 256 + tid;
        if (e < NE) atomicAdd(&deg[dstA[e]], 1.f);
    } else if (b < 8493){
        int t = (b - 8413) * 256 + tid;     // (s2s weight transposes)
        if (t < 8192){ int k = t >> 7, j = t & 127; lWihT[t] = lWih[(size_t)j * 64 + k]; }
        else if (t < 12288){ int t2 = t - 8192; int k = t2 >> 7, j = t2 & 127; lWhhT[t2] = lWhh[(size_t)j * 32 + k]; }
        else if (t < 14336){ int t2 = t - 12288; int k = t2 >> 5, c = t2 & 31; lin1T[t2] = lin1_W[(size_t)c * 64 + k]; }
    } else if (b < 8498){
        int g = (b - 8493) * 256 + tid;
        if (g > NB) return;
        int lo = 0, hi = NN;
        while (lo < hi){
            int mid = (lo + hi) >> 1;
            if (batch[mid] < g) lo = mid + 1; else hi = mid;
        }
        starts[g] = lo;
    } else {
        int t = (b - 8498) * 256 + tid;     // 14*64*8 = 7168 gateB entries
        if (t >= 7168) return;
        int tile = t >> 9;
        int l = (t >> 3) & 63;
        int i = t & 7;
        int m = l & 15, q = l >> 4;
        int k = q * 8 + i;
        float v;
        if (tile < 2){
            int c = tile * 16 + m;
            v = rootW[(size_t)k * 32 + c];
        } else if (tile < 8){
            int j = (tile - 2) * 16 + m;
            v = gWih[(size_t)j * 32 + k];
        } else {
            int j = (tile - 8) * 16 + m;
            v = gWhh[(size_t)j * 32 + k];
        }
        gateB[t] = (halfT)v;
    }
}

// =====================================================================
// k_msg4 R21: wave = 64 edges x ONE o-tile (8 waves = 4 edge-groups x 2
// o-tiles). Per ks: 1 LDS read feeds 4 MFMAs -> LDS bytes per edge-o
// halved vs R19. Same 391-block grid, 512 threads, 16-ks K-groups.
// Per-edge K summation order identical to R19 -> same absmax.
// =====================================================================
__global__ __launch_bounds__(512, 2) void k_msg4(
    const halfT* __restrict__ ehF, const halfT* __restrict__ BfF,
    const halfT* __restrict__ hH,
    const int* __restrict__ src, const int* __restrict__ dst,
    float* __restrict__ aggr)
{
    __shared__ halfT sB[2][16384];       // 2 x 32KB (16 ks per group)
    int tid = threadIdx.x;               // 0..511
    int l = tid & 63;
    int w = tid >> 6;                    // 0..7
    int eg = w >> 1, nt = w & 1;         // edge-group, o-tile
    int m = l & 15, q = l >> 4;
    int eb = blockIdx.x * 256 + eg * 64; // wave's 64 edges
    // stage group 0 -> LDS (512 threads x 4 half8 = 32KB)
    half8 pre[4];
    #pragma unroll
    for (int p = 0; p < 4; p++)
        pre[p] = *(const half8*)(BfF + (size_t)(p * 512 + tid) * 8);
    #pragma unroll
    for (int p = 0; p < 4; p++)
        *(half8*)(&sB[0][(p * 512 + tid) * 8]) = pre[p];
    // u fragments: 4 edge-tiles x 4 half8 (latency overlaps staging)
    int se[4];
    half8 u[4][4];
    #pragma unroll
    for (int T = 0; T < 4; T++){
        int e = eb + T * 16 + m;
        se[T] = (e < NE) ? src[e] : 0;
        const halfT* p0 = hH + (size_t)se[T] * 32;
        #pragma unroll
        for (int j = 0; j < 4; j++)
            u[T][j] = *(const half8*)(p0 + j * 8);
    }
    // eh fragments: 4 edge-tiles x 4 k-slices
    half8 eh[4][4];
    {
        int g0 = eb >> 4;
        #pragma unroll
        for (int T = 0; T < 4; T++)
            #pragma unroll
            for (int s = 0; s < 4; s++)
                eh[T][s] = *(const half8*)(ehF + ((size_t)((g0 + T) * 4 + s) * 64 + l) * 8);
    }
    __syncthreads();
    // prefetch group 1
    #pragma unroll
    for (int p = 0; p < 4; p++)
        pre[p] = *(const half8*)(BfF + (size_t)16384 + (size_t)(p * 512 + tid) * 8);
    f32x4 acc[4];
    #pragma unroll
    for (int T = 0; T < 4; T++) acc[T] = (f32x4){0,0,0,0};
    #pragma unroll
    for (int g = 0; g < 8; g++){
        const int cur = g & 1;
        #pragma unroll
        for (int j = 0; j < 16; j++){
            const int ks = g * 16 + j;
            half8 b = *(const half8*)(&sB[cur][((j * 2 + nt) * 512) + l * 8]);
            const int c = ks >> 2, s = ks & 3;
            #pragma unroll
            for (int T = 0; T < 4; T++){
                half8 a = eh[T][s] * u[T][c >> 3][c & 7];
                acc[T] = __builtin_amdgcn_mfma_f32_16x16x32_f16(a, b, acc[T], 0, 0, 0);
            }
        }
        if (g + 1 < 8){
            #pragma unroll
            for (int p = 0; p < 4; p++)
                *(half8*)(&sB[cur ^ 1][(p * 512 + tid) * 8]) = pre[p];
            if (g + 2 < 8){
                #pragma unroll
                for (int p = 0; p < 4; p++)
                    pre[p] = *(const half8*)(BfF + (size_t)(g + 2) * 16384 + (size_t)(p * 512 + tid) * 8);
            }
        }
        __syncthreads();
    }
    {   // bias K-tile (ks = 128): A = u[e][q*8+i] straight from hH (L2-hot)
        half8 b = *(const half8*)(BfF + (size_t)(256 + nt) * 512 + l * 8);
        #pragma unroll
        for (int T = 0; T < 4; T++){
            half8 ub = *(const half8*)(hH + (size_t)se[T] * 32 + q * 8);
            acc[T] = __builtin_amdgcn_mfma_f32_16x16x32_f16(ub, b, acc[T], 0, 0, 0);
        }
    }
    // scatter: lane holds msg[e = eb+T*16+q*4+r][o = nt*16+m]
    #pragma unroll
    for (int T = 0; T < 4; T++)
        #pragma unroll
        for (int r = 0; r < 4; r++){
            int e = eb + T * 16 + q * 4 + r;
            if (e < NE){
                int d = dst[e];
                atomicAdd(&aggr[(size_t)d * 32 + nt * 16 + m], acc[T][r]);
            }
        }
}

// =====================================================================
// k_gru: MFMA GRU (R17).  [unchanged]
// =====================================================================
__global__ __launch_bounds__(256) void k_gru(
    float* __restrict__ aggr, const float* __restrict__ deg,
    float* __restrict__ h, halfT* __restrict__ hH,
    const halfT* __restrict__ gateB,
    const float* __restrict__ gbih, const float* __restrict__ gbhh,
    const float* __restrict__ cb)
{
    __shared__ float hbuf[4][16][33];
    __shared__ float mbuf[4][16][33];
    int tid = threadIdx.x;
    int w = tid >> 6, l = tid & 63;
    int m16 = l & 15, q = l >> 4;
    int nb = blockIdx.x * 64 + w * 16;      // wave's base node
    float hv[8];
    const float* hp = h + (size_t)(nb + m16) * 32 + q * 8;
    *(float4*)&hv[0] = *(const float4*)(hp);
    *(float4*)&hv[4] = *(const float4*)(hp + 4);
    half8 h_hi, h_lo;
    #pragma unroll
    for (int i = 0; i < 8; i++){
        halfT hi = (halfT)hv[i];
        h_hi[i] = hi;
        h_lo[i] = (halfT)(hv[i] - (float)hi);
        hbuf[w][m16][q * 8 + i] = hv[i];
    }
    f32x4 macc0 = {0,0,0,0}, macc1 = {0,0,0,0};
    {
        half8 B0 = *(const half8*)(gateB + ((size_t)0 * 64 + l) * 8);
        half8 B1 = *(const half8*)(gateB + ((size_t)1 * 64 + l) * 8);
        macc0 = __builtin_amdgcn_mfma_f32_16x16x32_f16(h_hi, B0, macc0, 0, 0, 0);
        macc0 = __builtin_amdgcn_mfma_f32_16x16x32_f16(h_lo, B0, macc0, 0, 0, 0);
        macc1 = __builtin_amdgcn_mfma_f32_16x16x32_f16(h_hi, B1, macc1, 0, 0, 0);
        macc1 = __builtin_amdgcn_mfma_f32_16x16x32_f16(h_lo, B1, macc1, 0, 0, 0);
    }
    {
        float cb0 = cb[m16], cb1 = cb[16 + m16];
        #pragma unroll
        for (int r = 0; r < 4; r++){
            int nr = q * 4 + r;
            int node = nb + nr;
            float invd = 1.f / fmaxf(deg[node], 1.f);
            size_t a0 = (size_t)node * 32 + m16;
            size_t a1 = a0 + 16;
            float av0 = aggr[a0]; aggr[a0] = 0.f;
            float av1 = aggr[a1]; aggr[a1] = 0.f;
            float mv0 = fmaxf(macc0[r] + av0 * invd + cb0, 0.f);
            float mv1 = fmaxf(macc1[r] + av1 * invd + cb1, 0.f);
            mbuf[w][nr][m16]      = mv0;
            mbuf[w][nr][16 + m16] = mv1;
        }
    }
    __syncthreads();
    half8 m_hi, m_lo;
    #pragma unroll
    for (int i = 0; i < 8; i++){
        float mval = mbuf[w][m16][q * 8 + i];
        halfT hi = (halfT)mval;
        m_hi[i] = hi;
        m_lo[i] = (halfT)(mval - (float)hi);
    }
    f32x4 gx[6], gh[6];
    #pragma unroll
    for (int t = 0; t < 6; t++){ gx[t] = (f32x4){0,0,0,0}; gh[t] = (f32x4){0,0,0,0}; }
    #pragma unroll
    for (int t = 0; t < 6; t++){
        half8 Bx = *(const half8*)(gateB + ((size_t)(2 + t) * 64 + l) * 8);
        half8 Bh = *(const half8*)(gateB + ((size_t)(8 + t) * 64 + l) * 8);
        gx[t] = __builtin_amdgcn_mfma_f32_16x16x32_f16(m_hi, Bx, gx[t], 0, 0, 0);
        gx[t] = __builtin_amdgcn_mfma_f32_16x16x32_f16(m_lo, Bx, gx[t], 0, 0, 0);
        gh[t] = __builtin_amdgcn_mfma_f32_16x16x32_f16(h_hi, Bh, gh[t], 0, 0, 0);
        gh[t] = __builtin_amdgcn_mfma_f32_16x16x32_f16(h_lo, Bh, gh[t], 0, 0, 0);
    }
    #pragma unroll
    for (int t = 0; t < 2; t++){
        int c = t * 16 + m16;
        float bxr = gbih[c],      bhr = gbhh[c];
        float bxz = gbih[32 + c], bhz = gbhh[32 + c];
        float bxn = gbih[64 + c], bhn = gbhh[64 + c];
        #pragma unroll
        for (int r = 0; r < 4; r++){
            int nr = q * 4 + r;
            int node = nb + nr;
            float rr = sigf(gx[t][r] + bxr + gh[t][r] + bhr);
            float zz = sigf(gx[2 + t][r] + bxz + gh[2 + t][r] + bhz);
            float nn = tanh_f(gx[4 + t][r] + bxn + rr * (gh[4 + t][r] + bhn));
            float hq = hbuf[w][nr][c];
            float hnew = (1.f - zz) * nn + zz * hq;
            h[(size_t)node * 32 + c]  = hnew;
            hH[(size_t)node * 32 + c] = (halfT)hnew;
        }
    }
}

// =====================================================================
// k_s2s: LDS-cached Set2Set + final MLP.  [unchanged]
// =====================================================================
__global__ __launch_bounds__(64) void k_s2s(
    const float* __restrict__ h, const int* __restrict__ starts,
    const float* __restrict__ lWihT, const float* __restrict__ lWhhT,
    const float* __restrict__ lbih, const float* __restrict__ lbhh,
    const float* __restrict__ lin1T, const float* __restrict__ lin1_b,
    const float* __restrict__ lin2W, const float* __restrict__ lin2b,
    float* __restrict__ e_buf, float* __restrict__ out)
{
    __shared__ float hl[MAXN * 33];
    __shared__ float al[MAXN];
    __shared__ float hsl[32];
    int g = blockIdx.x, l = threadIdx.x;
    int s0 = starts[g], s1 = starts[g + 1];
    int n = s1 - s0;
    int c = l & 31, grp = l >> 5;
    int nl = (n < MAXN) ? n : MAXN;
    for (int idx = l; idx < nl * 32; idx += 64)
        hl[(idx >> 5) * 33 + (idx & 31)] = h[(size_t)s0 * 32 + idx];
    __syncthreads();
    float qs = 0.f, hsv = 0.f, csv = 0.f;
    for (int t = 0; t < 3; t++){
        float a1 = lbih[l] + lbhh[l];
        float a2 = lbih[l + 64] + lbhh[l + 64];
        #pragma unroll 8
        for (int k = 0; k < 64; k++){
            float qk = __shfl(qs, k);
            a1 += qk * lWihT[k * 128 + l];
            a2 += qk * lWihT[k * 128 + 64 + l];
        }
        #pragma unroll 8
        for (int k = 0; k < 32; k++){
            float hk = __shfl(qs, k);
            a1 += hk * lWhhT[k * 128 + l];
            a2 += hk * lWhhT[k * 128 + 64 + l];
        }
        float gate1 = sigf(a1);
        float gate2 = (l < 32) ? tanhf(a2) : sigf(a2);
        float fv = __shfl(gate1, c + 32);
        float ov = __shfl(gate2, c + 32);
        if (l < 32){
            csv = fv * csv + gate1 * gate2;
            hsv = ov * tanhf(csv);
            hsl[l] = hsv;
        }
        __syncthreads();
        float lmax = -3.4e38f;
        for (int i = l; i < n; i += 64){
            const float* hr = (i < MAXN) ? &hl[i * 33] : &h[(size_t)(s0 + i) * 32];
            float p = 0.f;
            #pragma unroll
            for (int c2 = 0; c2 < 32; c2++) p += hr[c2] * hsl[c2];
            if (i < MAXN) al[i] = p; else e_buf[s0 + i] = p;
            lmax = fmaxf(lmax, p);
        }
        #pragma unroll
        for (int o = 1; o < 64; o <<= 1) lmax = fmaxf(lmax, __shfl_xor(lmax, o));
        float lsum = 0.f;
        for (int i = l; i < n; i += 64){
            float e = (i < MAXN) ? al[i] : e_buf[s0 + i];
            float a = expf(e - lmax);
            if (i < MAXN) al[i] = a; else e_buf[s0 + i] = a;
            lsum += a;
        }
        #pragma unroll
        for (int o = 1; o < 64; o <<= 1) lsum += __shfl_xor(lsum, o);
        float inv = (lsum > 0.f) ? 1.f / lsum : 0.f;
        __syncthreads();
        float acc = 0.f;
        for (int i = grp; i < n; i += 2){
            float a = (i < MAXN) ? al[i] : e_buf[s0 + i];
            const float* hr = (i < MAXN) ? &hl[i * 33] : &h[(size_t)(s0 + i) * 32];
            acc += a * hr[c];
        }
        acc *= inv;
        acc += __shfl_xor(acc, 32);
        qs = (l < 32) ? hsv : acc;
        __syncthreads();
    }
    float s = lin1_b[c];
    #pragma unroll 8
    for (int k = 0; k < 64; k++){
        float qk = __shfl(qs, k);
        s += qk * lin1T[k * 32 + c];
    }
    float pp = (l < 32) ? fmaxf(s, 0.f) * lin2W[c] : 0.f;
    pp += __shfl_xor(pp, 1);  pp += __shfl_xor(pp, 2);
    pp += __shfl_xor(pp, 4);  pp += __shfl_xor(pp, 8);
    pp += __shfl_xor(pp, 16); pp += __shfl_xor(pp, 32);
    if (l == 0) out[g] = pp + lin2b[0];
}

extern "C" void kernel_launch(void* const* d_in, const int* in_sizes, int n_in,
                              void* d_out, int out_size, void* d_ws, size_t ws_size,
                              hipStream_t stream){
    (void)in_sizes; (void)n_in; (void)out_size;
    const float* x        = (const float*)d_in[0];
    const float* ea       = (const float*)d_in[1];
    const int*   ei       = (const int*)d_in[2];
    const int*   batch    = (const int*)d_in[3];
    const float* lin0_W   = (const float*)d_in[4];
    const float* lin0_b   = (const float*)d_in[5];
    const float* mlp_W1   = (const float*)d_in[6];
    const float* mlp_b1   = (const float*)d_in[7];
    const float* mlp_W2   = (const float*)d_in[8];
    const float* mlp_b2   = (const float*)d_in[9];
    const float* root_W   = (const float*)d_in[10];
    const float* conv_b   = (const float*)d_in[11];
    const float* gWih     = (const float*)d_in[12];
    const float* gWhh     = (const float*)d_in[13];
    const float* gbih     = (const float*)d_in[14];
    const float* gbhh     = (const float*)d_in[15];
    const float* lWih     = (const float*)d_in[16];
    const float* lWhh     = (const float*)d_in[17];
    const float* lbih     = (const float*)d_in[18];
    const float* lbhh     = (const float*)d_in[19];
    const float* lin1_W   = (const float*)d_in[20];
    const float* lin1_b   = (const float*)d_in[21];
    const float* lin2_W   = (const float*)d_in[22];
    const float* lin2_b   = (const float*)d_in[23];
    const int* src = ei;
    const int* dst = ei + NE;
    float* out = (float*)d_out;

    char* w = (char*)d_ws;
    size_t off = 0;
    auto alloc = [&](size_t bytes) -> void* {
        void* p = w + off;
        off = (off + bytes + 255) & ~(size_t)255;
        return p;
    };
    float* deg    = (float*)alloc((size_t)NN * 4);            // contiguous with aggr
    float* aggr   = (float*)alloc((size_t)NN * 32 * 4);
    float* h      = (float*)alloc((size_t)NN * 32 * 4);
    halfT* hH     = (halfT*)alloc((size_t)NN * 32 * 2);
    halfT* ehF    = (halfT*)alloc((size_t)NEP * 128 * 2);
    halfT* BfF    = (halfT*)alloc((size_t)129 * 2 * 64 * 8 * 2);
    int*   starts = (int*)alloc((size_t)(NB + 1) * 4);
    halfT* gateB  = (halfT*)alloc((size_t)14 * 64 * 8 * 2);
    float* lWihT  = (float*)alloc((size_t)8192 * 4);
    float* lWhhT  = (float*)alloc((size_t)4096 * 4);
    float* lin1T  = (float*)alloc((size_t)2048 * 4);
    float* e_buf  = (float*)alloc((size_t)NN * 4);
    if (ws_size < off) return;   // cannot run

    // zero deg+aggr (contiguous, NN + NN*32 = 1,320,000 floats = 330,000 float4)
    k_zero<<<(330000 + 255) / 256, 256, 0, stream>>>((float4*)deg, 330000);

    k_setup<<<8526, 256, 0, stream>>>(x, lin0_W, lin0_b, ea, mlp_W1, mlp_b1,
        mlp_W2, mlp_b2, dst, batch, root_W, gWih, gWhh, lWih, lWhh, lin1_W,
        h, hH, ehF, BfF, deg, gateB, lWihT, lWhhT, lin1T, starts);

    for (int t = 0; t < 3; t++){
        k_msg4<<<NEP / 256, 512, 0, stream>>>(ehF, BfF, hH, src, dst, aggr);
        k_gru<<<NN / 64, 256, 0, stream>>>(aggr, deg, h, hH, gateB,
                                           gbih, gbhh, conv_b);
    }
    k_s2s<<<NB, 64, 0, stream>>>(h, starts, lWihT, lWhhT, lbih, lbhh,
                                 lin1T, lin1_b, lin2_W, lin2_b, e_buf, out);
}

// Round 22
// 183.612 us; speedup vs baseline: 1.3644x; 1.3644x over previous
//
#include <hip/hip_runtime.h>
#include <hip/hip_bf16.h>
#include <cstdint>

#define NN 40000
#define NE 100000
#define NEP 100096           // 256-aligned edge count
#define NB 1024
#define MAXN 192             // per-graph LDS node cache capacity

typedef _Float16 halfT;
typedef _Float16 half8 __attribute__((ext_vector_type(8)));
typedef float f32x4 __attribute__((ext_vector_type(4)));

static __device__ __forceinline__ float sigf(float x){ return 1.f/(1.f + __expf(-x)); }
static __device__ __forceinline__ float tanh_f(float x){ float e = __expf(2.f * x); return 1.f - 2.f/(e + 1.f); }

// ---------------- fast zero ----------------
__global__ __launch_bounds__(256) void k_zero(float4* __restrict__ p, int n4){
    int i = blockIdx.x * 256 + threadIdx.x;
    if (i < n4) p[i] = make_float4(0.f, 0.f, 0.f, 0.f);
}

// =====================================================================
// k_setup: one kernel, 7 block-ranges.  [unchanged from R17]
// =====================================================================
__global__ __launch_bounds__(256) void k_setup(
    const float* __restrict__ x, const float* __restrict__ lin0_W, const float* __restrict__ lin0_b,
    const float* __restrict__ ea, const float* __restrict__ W1, const float* __restrict__ b1,
    const float* __restrict__ W2, const float* __restrict__ b2,
    const int* __restrict__ dstA, const int* __restrict__ batch,
    const float* __restrict__ rootW,
    const float* __restrict__ gWih, const float* __restrict__ gWhh,
    const float* __restrict__ lWih, const float* __restrict__ lWhh, const float* __restrict__ lin1_W,
    float* __restrict__ h, halfT* __restrict__ hH, halfT* __restrict__ ehF, halfT* __restrict__ BfF,
    float* __restrict__ deg, halfT* __restrict__ gateB,
    float* __restrict__ lWihT, float* __restrict__ lWhhT, float* __restrict__ lin1T,
    int* __restrict__ starts)
{
    int b = blockIdx.x, tid = threadIdx.x;
    if (b < 1250){
        __shared__ float sW[32 * 30];
        __shared__ float sB[32];
        for (int idx = tid; idx < 960; idx += 256) sW[idx] = lin0_W[idx];
        if (tid < 32) sB[tid] = lin0_b[tid];
        __syncthreads();
        int t8 = b * 256 + tid;             // [0, NN*8)
        int i = t8 >> 3, q4 = t8 & 7;       // node, channel-quad
        const float* xr = x + (size_t)i * 30;
        float xv[30];
        #pragma unroll
        for (int f = 0; f < 30; f++) xv[f] = xr[f];
        float r[4];
        #pragma unroll
        for (int cc = 0; cc < 4; cc++){
            int c = q4 * 4 + cc;
            const float* wr = &sW[c * 30];
            float s = sB[c];
            #pragma unroll
            for (int f = 0; f < 30; f++) s += xv[f] * wr[f];
            r[cc] = fmaxf(s, 0.f);
        }
        *(float4*)(h + (size_t)i * 32 + q4 * 4) = *(float4*)r;
        halfT rh[4];
        #pragma unroll
        for (int cc = 0; cc < 4; cc++) rh[cc] = (halfT)r[cc];
        *(uint2*)(hH + (size_t)i * 32 + q4 * 4) = *(uint2*)rh;
    } else if (b < 7506){
        __shared__ float sW1[128 * 11];
        __shared__ float sb1[128];
        for (int idx = tid; idx < 1408; idx += 256) sW1[idx] = W1[idx];
        if (tid < 128) sb1[tid] = b1[tid];
        __syncthreads();
        int t8 = (b - 1250) * 256 + tid;    // [0, NEP*16)
        int ch = t8 & 63;
        int s4 = (t8 >> 6) & 3;
        int g16 = t8 >> 8;
        int m = ch & 15, q = ch >> 4;       // lane-linear content
        int e = g16 * 16 + m;
        int kb = 32 * s4 + q * 8;
        halfT v[8];
        if (e < NE){
            const float* xr = ea + (size_t)e * 11;
            float xv[11];
            #pragma unroll
            for (int f = 0; f < 11; f++) xv[f] = xr[f];
            #pragma unroll
            for (int i8 = 0; i8 < 8; i8++){
                int k = kb + i8;
                const float* wr = &sW1[k * 11];
                float s = sb1[k];
                #pragma unroll
                for (int f = 0; f < 11; f++) s += xv[f] * wr[f];
                v[i8] = (halfT)fmaxf(s, 0.f);
            }
        } else {
            #pragma unroll
            for (int i8 = 0; i8 < 8; i8++) v[i8] = (halfT)0.f;
        }
        *(half8*)(ehF + (size_t)t8 * 8) = *(half8*)v;
    } else if (b < 8022){
        int gid = (b - 7506) * 256 + tid;   // 129*2*64*8 = 132096
        int i8 = gid & 7;
        int ch = (gid >> 3) & 63;
        int nt = (gid >> 9) & 1;
        int ks = gid >> 10;
        int m = ch & 15, q = ch >> 4;       // lane-linear content
        int o = nt * 16 + m;
        float v;
        if (ks < 128){
            int c = ks >> 2;
            int k = 32 * (ks & 3) + q * 8 + i8;
            v = W2[(size_t)(c * 32 + o) * 128 + k];
        } else {
            int c = q * 8 + i8;
            v = b2[c * 32 + o];
        }
        BfF[gid] = (halfT)v;
    } else if (b < 8413){
        int e = (b - 8022) * 256 + tid;
        if (e < NE) atomicAdd(&deg[dstA[e]], 1.f);
    } else if (b < 8493){
        int t = (b - 8413) * 256 + tid;     // (s2s weight transposes)
        if (t < 8192){ int k = t >> 7, j = t & 127; lWihT[t] = lWih[(size_t)j * 64 + k]; }
        else if (t < 12288){ int t2 = t - 8192; int k = t2 >> 7, j = t2 & 127; lWhhT[t2] = lWhh[(size_t)j * 32 + k]; }
        else if (t < 14336){ int t2 = t - 12288; int k = t2 >> 5, c = t2 & 31; lin1T[t2] = lin1_W[(size_t)c * 64 + k]; }
    } else if (b < 8498){
        int g = (b - 8493) * 256 + tid;
        if (g > NB) return;
        int lo = 0, hi = NN;
        while (lo < hi){
            int mid = (lo + hi) >> 1;
            if (batch[mid] < g) lo = mid + 1; else hi = mid;
        }
        starts[g] = lo;
    } else {
        int t = (b - 8498) * 256 + tid;     // 14*64*8 = 7168 gateB entries
        if (t >= 7168) return;
        int tile = t >> 9;
        int l = (t >> 3) & 63;
        int i = t & 7;
        int m = l & 15, q = l >> 4;
        int k = q * 8 + i;
        float v;
        if (tile < 2){
            int c = tile * 16 + m;
            v = rootW[(size_t)k * 32 + c];
        } else if (tile < 8){
            int j = (tile - 2) * 16 + m;
            v = gWih[(size_t)j * 32 + k];
        } else {
            int j = (tile - 8) * 16 + m;
            v = gWhh[(size_t)j * 32 + k];
        }
        gateB[t] = (halfT)v;
    }
}

// =====================================================================
// k_msg4 (REVERTED to R19-measured version): wave = 32 edges x 2 o-tiles,
// 16-ks K-groups (2 x 32KB double-buffered LDS), 512 threads, 8 waves
// share one staging. Best measured: ~28 us/dispatch, total 183.4.
// =====================================================================
__global__ __launch_bounds__(512, 4) void k_msg4(
    const halfT* __restrict__ ehF, const halfT* __restrict__ BfF,
    const halfT* __restrict__ hH,
    const int* __restrict__ src, const int* __restrict__ dst,
    float* __restrict__ aggr)
{
    __shared__ halfT sB[2][16384];       // 2 x 32KB (16 ks per group)
    int tid = threadIdx.x;               // 0..511
    int l = tid & 63;
    int wid = blockIdx.x * 8 + (tid >> 6);
    int m = l & 15, q = l >> 4;
    int eb = wid * 32;
    half8 pre[4];
    #pragma unroll
    for (int p = 0; p < 4; p++)
        pre[p] = *(const half8*)(BfF + (size_t)(p * 512 + tid) * 8);
    #pragma unroll
    for (int p = 0; p < 4; p++)
        *(half8*)(&sB[0][(p * 512 + tid) * 8]) = pre[p];
    half8 u0[4], u1[4], ub0, ub1;
    {
        int e0 = eb + m;      int se0 = (e0 < NE) ? src[e0] : 0;
        int e1 = eb + 16 + m; int se1 = (e1 < NE) ? src[e1] : 0;
        const halfT* p0 = hH + (size_t)se0 * 32;
        const halfT* p1 = hH + (size_t)se1 * 32;
        #pragma unroll
        for (int j = 0; j < 4; j++){
            u0[j] = *(const half8*)(p0 + j * 8);
            u1[j] = *(const half8*)(p1 + j * 8);
        }
        ub0 = *(const half8*)(p0 + q * 8);
        ub1 = *(const half8*)(p1 + q * 8);
    }
    half8 eh0[4], eh1[4];
    {
        int g0 = eb >> 4;
        #pragma unroll
        for (int s = 0; s < 4; s++){
            eh0[s] = *(const half8*)(ehF + ((size_t)(g0 * 4 + s) * 64 + l) * 8);
            eh1[s] = *(const half8*)(ehF + ((size_t)((g0 + 1) * 4 + s) * 64 + l) * 8);
        }
    }
    __syncthreads();
    #pragma unroll
    for (int p = 0; p < 4; p++)
        pre[p] = *(const half8*)(BfF + (size_t)16384 + (size_t)(p * 512 + tid) * 8);
    f32x4 acc00 = {0,0,0,0}, acc01 = {0,0,0,0}, acc10 = {0,0,0,0}, acc11 = {0,0,0,0};
    #pragma unroll
    for (int g = 0; g < 8; g++){
        const int cur = g & 1;
        #pragma unroll
        for (int j = 0; j < 16; j++){
            const int ks = g * 16 + j;
            half8 b0 = *(const half8*)(&sB[cur][(j * 2 + 0) * 512 + l * 8]);
            half8 b1 = *(const half8*)(&sB[cur][(j * 2 + 1) * 512 + l * 8]);
            const int c = ks >> 2, s = ks & 3;
            halfT uc0 = u0[c >> 3][c & 7];
            halfT uc1 = u1[c >> 3][c & 7];
            half8 a0 = eh0[s] * uc0;
            half8 a1 = eh1[s] * uc1;
            acc00 = __builtin_amdgcn_mfma_f32_16x16x32_f16(a0, b0, acc00, 0, 0, 0);
            acc01 = __builtin_amdgcn_mfma_f32_16x16x32_f16(a0, b1, acc01, 0, 0, 0);
            acc10 = __builtin_amdgcn_mfma_f32_16x16x32_f16(a1, b0, acc10, 0, 0, 0);
            acc11 = __builtin_amdgcn_mfma_f32_16x16x32_f16(a1, b1, acc11, 0, 0, 0);
        }
        if (g + 1 < 8){
            #pragma unroll
            for (int p = 0; p < 4; p++)
                *(half8*)(&sB[cur ^ 1][(p * 512 + tid) * 8]) = pre[p];
            if (g + 2 < 8){
                #pragma unroll
                for (int p = 0; p < 4; p++)
                    pre[p] = *(const half8*)(BfF + (size_t)(g + 2) * 16384 + (size_t)(p * 512 + tid) * 8);
            }
        }
        __syncthreads();
    }
    {
        half8 b0 = *(const half8*)(BfF + (size_t)256 * 512 + l * 8);
        half8 b1 = *(const half8*)(BfF + (size_t)257 * 512 + l * 8);
        acc00 = __builtin_amdgcn_mfma_f32_16x16x32_f16(ub0, b0, acc00, 0, 0, 0);
        acc01 = __builtin_amdgcn_mfma_f32_16x16x32_f16(ub0, b1, acc01, 0, 0, 0);
        acc10 = __builtin_amdgcn_mfma_f32_16x16x32_f16(ub1, b0, acc10, 0, 0, 0);
        acc11 = __builtin_amdgcn_mfma_f32_16x16x32_f16(ub1, b1, acc11, 0, 0, 0);
    }
    #pragma unroll
    for (int r = 0; r < 4; r++){
        int ea0 = eb + q * 4 + r;
        if (ea0 < NE){
            int d = dst[ea0];
            atomicAdd(&aggr[(size_t)d * 32 + m],      acc00[r]);
            atomicAdd(&aggr[(size_t)d * 32 + 16 + m], acc01[r]);
        }
        int ea1 = eb + 16 + q * 4 + r;
        if (ea1 < NE){
            int d = dst[ea1];
            atomicAdd(&aggr[(size_t)d * 32 + m],      acc10[r]);
            atomicAdd(&aggr[(size_t)d * 32 + 16 + m], acc11[r]);
        }
    }
}

// =====================================================================
// k_gru: MFMA GRU (R17).  [unchanged]
// =====================================================================
__global__ __launch_bounds__(256) void k_gru(
    float* __restrict__ aggr, const float* __restrict__ deg,
    float* __restrict__ h, halfT* __restrict__ hH,
    const halfT* __restrict__ gateB,
    const float* __restrict__ gbih, const float* __restrict__ gbhh,
    const float* __restrict__ cb)
{
    __shared__ float hbuf[4][16][33];
    __shared__ float mbuf[4][16][33];
    int tid = threadIdx.x;
    int w = tid >> 6, l = tid & 63;
    int m16 = l & 15, q = l >> 4;
    int nb = blockIdx.x * 64 + w * 16;      // wave's base node
    float hv[8];
    const float* hp = h + (size_t)(nb + m16) * 32 + q * 8;
    *(float4*)&hv[0] = *(const float4*)(hp);
    *(float4*)&hv[4] = *(const float4*)(hp + 4);
    half8 h_hi, h_lo;
    #pragma unroll
    for (int i = 0; i < 8; i++){
        halfT hi = (halfT)hv[i];
        h_hi[i] = hi;
        h_lo[i] = (halfT)(hv[i] - (float)hi);
        hbuf[w][m16][q * 8 + i] = hv[i];
    }
    f32x4 macc0 = {0,0,0,0}, macc1 = {0,0,0,0};
    {
        half8 B0 = *(const half8*)(gateB + ((size_t)0 * 64 + l) * 8);
        half8 B1 = *(const half8*)(gateB + ((size_t)1 * 64 + l) * 8);
        macc0 = __builtin_amdgcn_mfma_f32_16x16x32_f16(h_hi, B0, macc0, 0, 0, 0);
        macc0 = __builtin_amdgcn_mfma_f32_16x16x32_f16(h_lo, B0, macc0, 0, 0, 0);
        macc1 = __builtin_amdgcn_mfma_f32_16x16x32_f16(h_hi, B1, macc1, 0, 0, 0);
        macc1 = __builtin_amdgcn_mfma_f32_16x16x32_f16(h_lo, B1, macc1, 0, 0, 0);
    }
    {
        float cb0 = cb[m16], cb1 = cb[16 + m16];
        #pragma unroll
        for (int r = 0; r < 4; r++){
            int nr = q * 4 + r;
            int node = nb + nr;
            float invd = 1.f / fmaxf(deg[node], 1.f);
            size_t a0 = (size_t)node * 32 + m16;
            size_t a1 = a0 + 16;
            float av0 = aggr[a0]; aggr[a0] = 0.f;
            float av1 = aggr[a1]; aggr[a1] = 0.f;
            float mv0 = fmaxf(macc0[r] + av0 * invd + cb0, 0.f);
            float mv1 = fmaxf(macc1[r] + av1 * invd + cb1, 0.f);
            mbuf[w][nr][m16]      = mv0;
            mbuf[w][nr][16 + m16] = mv1;
        }
    }
    __syncthreads();
    half8 m_hi, m_lo;
    #pragma unroll
    for (int i = 0; i < 8; i++){
        float mval = mbuf[w][m16][q * 8 + i];
        halfT hi = (halfT)mval;
        m_hi[i] = hi;
        m_lo[i] = (halfT)(mval - (float)hi);
    }
    f32x4 gx[6], gh[6];
    #pragma unroll
    for (int t = 0; t < 6; t++){ gx[t] = (f32x4){0,0,0,0}; gh[t] = (f32x4){0,0,0,0}; }
    #pragma unroll
    for (int t = 0; t < 6; t++){
        half8 Bx = *(const half8*)(gateB + ((size_t)(2 + t) * 64 + l) * 8);
        half8 Bh = *(const half8*)(gateB + ((size_t)(8 + t) * 64 + l) * 8);
        gx[t] = __builtin_amdgcn_mfma_f32_16x16x32_f16(m_hi, Bx, gx[t], 0, 0, 0);
        gx[t] = __builtin_amdgcn_mfma_f32_16x16x32_f16(m_lo, Bx, gx[t], 0, 0, 0);
        gh[t] = __builtin_amdgcn_mfma_f32_16x16x32_f16(h_hi, Bh, gh[t], 0, 0, 0);
        gh[t] = __builtin_amdgcn_mfma_f32_16x16x32_f16(h_lo, Bh, gh[t], 0, 0, 0);
    }
    #pragma unroll
    for (int t = 0; t < 2; t++){
        int c = t * 16 + m16;
        float bxr = gbih[c],      bhr = gbhh[c];
        float bxz = gbih[32 + c], bhz = gbhh[32 + c];
        float bxn = gbih[64 + c], bhn = gbhh[64 + c];
        #pragma unroll
        for (int r = 0; r < 4; r++){
            int nr = q * 4 + r;
            int node = nb + nr;
            float rr = sigf(gx[t][r] + bxr + gh[t][r] + bhr);
            float zz = sigf(gx[2 + t][r] + bxz + gh[2 + t][r] + bhz);
            float nn = tanh_f(gx[4 + t][r] + bxn + rr * (gh[4 + t][r] + bhn));
            float hq = hbuf[w][nr][c];
            float hnew = (1.f - zz) * nn + zz * hq;
            h[(size_t)node * 32 + c]  = hnew;
            hH[(size_t)node * 32 + c] = (halfT)hnew;
        }
    }
}

// =====================================================================
// k_s2s: LDS-cached Set2Set + final MLP.  [unchanged]
// =====================================================================
__global__ __launch_bounds__(64) void k_s2s(
    const float* __restrict__ h, const int* __restrict__ starts,
    const float* __restrict__ lWihT, const float* __restrict__ lWhhT,
    const float* __restrict__ lbih, const float* __restrict__ lbhh,
    const float* __restrict__ lin1T, const float* __restrict__ lin1_b,
    const float* __restrict__ lin2W, const float* __restrict__ lin2b,
    float* __restrict__ e_buf, float* __restrict__ out)
{
    __shared__ float hl[MAXN * 33];
    __shared__ float al[MAXN];
    __shared__ float hsl[32];
    int g = blockIdx.x, l = threadIdx.x;
    int s0 = starts[g], s1 = starts[g + 1];
    int n = s1 - s0;
    int c = l & 31, grp = l >> 5;
    int nl = (n < MAXN) ? n : MAXN;
    for (int idx = l; idx < nl * 32; idx += 64)
        hl[(idx >> 5) * 33 + (idx & 31)] = h[(size_t)s0 * 32 + idx];
    __syncthreads();
    float qs = 0.f, hsv = 0.f, csv = 0.f;
    for (int t = 0; t < 3; t++){
        float a1 = lbih[l] + lbhh[l];
        float a2 = lbih[l + 64] + lbhh[l + 64];
        #pragma unroll 8
        for (int k = 0; k < 64; k++){
            float qk = __shfl(qs, k);
            a1 += qk * lWihT[k * 128 + l];
            a2 += qk * lWihT[k * 128 + 64 + l];
        }
        #pragma unroll 8
        for (int k = 0; k < 32; k++){
            float hk = __shfl(qs, k);
            a1 += hk * lWhhT[k * 128 + l];
            a2 += hk * lWhhT[k * 128 + 64 + l];
        }
        float gate1 = sigf(a1);
        float gate2 = (l < 32) ? tanhf(a2) : sigf(a2);
        float fv = __shfl(gate1, c + 32);
        float ov = __shfl(gate2, c + 32);
        if (l < 32){
            csv = fv * csv + gate1 * gate2;
            hsv = ov * tanhf(csv);
            hsl[l] = hsv;
        }
        __syncthreads();
        float lmax = -3.4e38f;
        for (int i = l; i < n; i += 64){
            const float* hr = (i < MAXN) ? &hl[i * 33] : &h[(size_t)(s0 + i) * 32];
            float p = 0.f;
            #pragma unroll
            for (int c2 = 0; c2 < 32; c2++) p += hr[c2] * hsl[c2];
            if (i < MAXN) al[i] = p; else e_buf[s0 + i] = p;
            lmax = fmaxf(lmax, p);
        }
        #pragma unroll
        for (int o = 1; o < 64; o <<= 1) lmax = fmaxf(lmax, __shfl_xor(lmax, o));
        float lsum = 0.f;
        for (int i = l; i < n; i += 64){
            float e = (i < MAXN) ? al[i] : e_buf[s0 + i];
            float a = expf(e - lmax);
            if (i < MAXN) al[i] = a; else e_buf[s0 + i] = a;
            lsum += a;
        }
        #pragma unroll
        for (int o = 1; o < 64; o <<= 1) lsum += __shfl_xor(lsum, o);
        float inv = (lsum > 0.f) ? 1.f / lsum : 0.f;
        __syncthreads();
        float acc = 0.f;
        for (int i = grp; i < n; i += 2){
            float a = (i < MAXN) ? al[i] : e_buf[s0 + i];
            const float* hr = (i < MAXN) ? &hl[i * 33] : &h[(size_t)(s0 + i) * 32];
            acc += a * hr[c];
        }
        acc *= inv;
        acc += __shfl_xor(acc, 32);
        qs = (l < 32) ? hsv : acc;
        __syncthreads();
    }
    float s = lin1_b[c];
    #pragma unroll 8
    for (int k = 0; k < 64; k++){
        float qk = __shfl(qs, k);
        s += qk * lin1T[k * 32 + c];
    }
    float pp = (l < 32) ? fmaxf(s, 0.f) * lin2W[c] : 0.f;
    pp += __shfl_xor(pp, 1);  pp += __shfl_xor(pp, 2);
    pp += __shfl_xor(pp, 4);  pp += __shfl_xor(pp, 8);
    pp += __shfl_xor(pp, 16); pp += __shfl_xor(pp, 32);
    if (l == 0) out[g] = pp + lin2b[0];
}

extern "C" void kernel_launch(void* const* d_in, const int* in_sizes, int n_in,
                              void* d_out, int out_size, void* d_ws, size_t ws_size,
                              hipStream_t stream){
    (void)in_sizes; (void)n_in; (void)out_size;
    const float* x        = (const float*)d_in[0];
    const float* ea       = (const float*)d_in[1];
    const int*   ei       = (const int*)d_in[2];
    const int*   batch    = (const int*)d_in[3];
    const float* lin0_W   = (const float*)d_in[4];
    const float* lin0_b   = (const float*)d_in[5];
    const float* mlp_W1   = (const float*)d_in[6];
    const float* mlp_b1   = (const float*)d_in[7];
    const float* mlp_W2   = (const float*)d_in[8];
    const float* mlp_b2   = (const float*)d_in[9];
    const float* root_W   = (const float*)d_in[10];
    const float* conv_b   = (const float*)d_in[11];
    const float* gWih     = (const float*)d_in[12];
    const float* gWhh     = (const float*)d_in[13];
    const float* gbih     = (const float*)d_in[14];
    const float* gbhh     = (const float*)d_in[15];
    const float* lWih     = (const float*)d_in[16];
    const float* lWhh     = (const float*)d_in[17];
    const float* lbih     = (const float*)d_in[18];
    const float* lbhh     = (const float*)d_in[19];
    const float* lin1_W   = (const float*)d_in[20];
    const float* lin1_b   = (const float*)d_in[21];
    const float* lin2_W   = (const float*)d_in[22];
    const float* lin2_b   = (const float*)d_in[23];
    const int* src = ei;
    const int* dst = ei + NE;
    float* out = (float*)d_out;

    char* w = (char*)d_ws;
    size_t off = 0;
    auto alloc = [&](size_t bytes) -> void* {
        void* p = w + off;
        off = (off + bytes + 255) & ~(size_t)255;
        return p;
    };
    float* deg    = (float*)alloc((size_t)NN * 4);            // contiguous with aggr
    float* aggr   = (float*)alloc((size_t)NN * 32 * 4);
    float* h      = (float*)alloc((size_t)NN * 32 * 4);
    halfT* hH     = (halfT*)alloc((size_t)NN * 32 * 2);
    halfT* ehF    = (halfT*)alloc((size_t)NEP * 128 * 2);
    halfT* BfF    = (halfT*)alloc((size_t)129 * 2 * 64 * 8 * 2);
    int*   starts = (int*)alloc((size_t)(NB + 1) * 4);
    halfT* gateB  = (halfT*)alloc((size_t)14 * 64 * 8 * 2);
    float* lWihT  = (float*)alloc((size_t)8192 * 4);
    float* lWhhT  = (float*)alloc((size_t)4096 * 4);
    float* lin1T  = (float*)alloc((size_t)2048 * 4);
    float* e_buf  = (float*)alloc((size_t)NN * 4);
    if (ws_size < off) return;   // cannot run

    // zero deg+aggr (contiguous, NN + NN*32 = 1,320,000 floats = 330,000 float4)
    k_zero<<<(330000 + 255) / 256, 256, 0, stream>>>((float4*)deg, 330000);

    k_setup<<<8526, 256, 0, stream>>>(x, lin0_W, lin0_b, ea, mlp_W1, mlp_b1,
        mlp_W2, mlp_b2, dst, batch, root_W, gWih, gWhh, lWih, lWhh, lin1_W,
        h, hH, ehF, BfF, deg, gateB, lWihT, lWhhT, lin1T, starts);

    for (int t = 0; t < 3; t++){
        k_msg4<<<NEP / 256, 512, 0, stream>>>(ehF, BfF, hH, src, dst, aggr);
        k_gru<<<NN / 64, 256, 0, stream>>>(aggr, deg, h, hH, gateB,
                                           gbih, gbhh, conv_b);
    }
    k_s2s<<<NB, 64, 0, stream>>>(h, starts, lWihT, lWhhT, lbih, lbhh,
                                 lin1T, lin1_b, lin2_W, lin2_b, e_buf, out);
}